// Round 4
// baseline (418.680 us; speedup 1.0000x reference)
//
#include <hip/hip_runtime.h>
#include <math.h>

#define FLOOR_EPS 1e-6f
#define T_LEN 8000
#define C_CH 40
#define N_ROWS (128 * 40)
#define CHUNKS 4
#define CHUNK_MAX 2048        // chunk starts: 0,2048,4096,6144 (last len 1856)
#define LOOKBACK 512          // q^512 = 0.96^512 ~ 8.6e-10 -> exact to fp32
#define EPL 32                // elems per lane (contiguous)
#define WAVES_PER_BLOCK 4

typedef float f32x4 __attribute__((ext_vector_type(4)));

__device__ __forceinline__ float fast_log2(float v) { return __builtin_amdgcn_logf(v); }
__device__ __forceinline__ float fast_exp2(float v) { return __builtin_amdgcn_exp2f(v); }
__device__ __forceinline__ float fast_sqrt(float v) { return __builtin_amdgcn_sqrtf(v); }

// One wave per (row, chunk). Lane l owns 32 CONTIGUOUS elems of the chunk.
// All loads issue upfront; ONE 6-step shuffle scan per chunk (vs 8 before).
// EMA: s_t = q*s_{t-1} + w*x_t, s_{-1} = x[0].
__global__ __launch_bounds__(256) void pcen_kernel(
    const float* __restrict__ x,
    const float* __restrict__ alpha,
    const float* __restrict__ delta,
    const float* __restrict__ root,
    const float* __restrict__ ema_w,
    float* __restrict__ out)
{
    const int wave  = threadIdx.x >> 6;
    const int lane  = threadIdx.x & 63;
    const int gid   = blockIdx.x * WAVES_PER_BLOCK + wave;
    const int row   = gid >> 2;          // CHUNKS == 4
    const int chunk = gid & 3;
    if (row >= N_ROWS) return;
    const int c = row % C_CH;

    const float w     = fminf(fmaxf(ema_w[c], 0.0f), 1.0f);
    const float q     = 1.0f - w;
    const float a     = fminf(alpha[c], 1.0f);
    const float inv_r = 1.0f / fmaxf(root[c], 1.0f);
    const float d     = delta[c];
    const float d_pow = powf(d, inv_r);
    const bool  use_sqrt = (inv_r == 0.5f);

    // q^(8*2^k), k=0..5 : q^8,16,32,64,128,256 (lookback scale + scan weights)
    const float q2 = q * q, q4 = q2 * q2;
    float q8p[6];
    q8p[0] = q4 * q4;
    #pragma unroll
    for (int k = 1; k < 6; ++k) q8p[k] = q8p[k - 1] * q8p[k - 1];
    const float q8  = q8p[0];
    const float q32 = q8p[2];

    // scan weights q^(32*2^k) = q8p[k+2] for k=0..3, then square on
    float q32p[6];
    q32p[0] = q8p[2]; q32p[1] = q8p[3]; q32p[2] = q8p[4]; q32p[3] = q8p[5];
    q32p[4] = q32p[3] * q32p[3];
    q32p[5] = q32p[4] * q32p[4];

    // qp = q^(32*lane)
    float qp = 1.0f;
    #pragma unroll
    for (int k = 0; k < 6; ++k)
        if ((lane >> k) & 1) qp *= q32p[k];

    const int start  = chunk * CHUNK_MAX;            // within row
    const int estart = start + lane * EPL;           // within row
    const bool valid = estart < T_LEN;               // chunk 3: lanes >= 58 idle
    const size_t gbase = (size_t)row * T_LEN + estart;

    // ---- all loads upfront ----
    float4 xv[8];
    if (valid) {
        const float4* xp = (const float4*)(x + gbase);
        #pragma unroll
        for (int j = 0; j < 8; ++j) xv[j] = xp[j];
    } else {
        #pragma unroll
        for (int j = 0; j < 8; ++j) xv[j] = make_float4(0.f, 0.f, 0.f, 0.f);
    }

    float s_carry;
    if (chunk == 0) {
        s_carry = __shfl(xv[0].x, 0, 64);            // s_{-1} = x[0]
    } else {
        // s_start = ema[row, start-1] ~= sum_{j<512} w q^j x[start-1-j]
        const float4* lp = (const float4*)(x + (size_t)row * T_LEN + start - LOOKBACK + lane * 8);
        float4 a0 = lp[0];
        float4 a1 = lp[1];
        float v = a0.x;
        v = fmaf(v, q, a0.y); v = fmaf(v, q, a0.z); v = fmaf(v, q, a0.w);
        v = fmaf(v, q, a1.x); v = fmaf(v, q, a1.y); v = fmaf(v, q, a1.z); v = fmaf(v, q, a1.w);
        float S = w * v;
        const int m = 63 - lane;                     // scale = q^(8*m)
        float scale = 1.0f;
        #pragma unroll
        for (int k = 0; k < 6; ++k)
            if ((m >> k) & 1) scale *= q8p[k];
        S *= scale;
        #pragma unroll
        for (int k = 0; k < 6; ++k)
            S += __shfl_xor(S, 1 << k, 64);
        s_carry = S;
    }

    // ---- lane-local fold over 32 elems: 4 parallel 8-deep chains ----
    float h[4];
    #pragma unroll
    for (int g = 0; g < 4; ++g) {
        float t = xv[2 * g].x;
        t = fmaf(t, q, xv[2 * g].y);
        t = fmaf(t, q, xv[2 * g].z);
        t = fmaf(t, q, xv[2 * g].w);
        t = fmaf(t, q, xv[2 * g + 1].x);
        t = fmaf(t, q, xv[2 * g + 1].y);
        t = fmaf(t, q, xv[2 * g + 1].z);
        t = fmaf(t, q, xv[2 * g + 1].w);
        h[g] = t;
    }
    float bt = h[0];
    bt = fmaf(bt, q8, h[1]);
    bt = fmaf(bt, q8, h[2]);
    bt = fmaf(bt, q8, h[3]);
    float B = w * bt;

    // ---- single 6-step inclusive wave scan, weights q^(32*offset) ----
    #pragma unroll
    for (int k = 0; k < 6; ++k) {
        float Bp = __shfl_up(B, 1u << k, 64);
        if (lane >= (1 << k)) B = fmaf(q32p[k], Bp, B);
    }
    float Bexcl = __shfl_up(B, 1, 64);
    if (lane == 0) Bexcl = 0.0f;

    // state entering this lane's first element
    float e = fmaf(qp, s_carry, Bexcl);

    // ---- per-element EMA + output ----
    f32x4* op = (f32x4*)(out + gbase);
    #pragma unroll
    for (int g = 0; g < 8; ++g) {
        float e0 = fmaf(q, e,  w * xv[g].x);
        float e1 = fmaf(q, e0, w * xv[g].y);
        float e2 = fmaf(q, e1, w * xv[g].z);
        float e3 = fmaf(q, e2, w * xv[g].w);
        e = e3;

        float y0 = fmaf(xv[g].x, fast_exp2(-a * fast_log2(FLOOR_EPS + e0)), d);
        float y1 = fmaf(xv[g].y, fast_exp2(-a * fast_log2(FLOOR_EPS + e1)), d);
        float y2 = fmaf(xv[g].z, fast_exp2(-a * fast_log2(FLOOR_EPS + e2)), d);
        float y3 = fmaf(xv[g].w, fast_exp2(-a * fast_log2(FLOOR_EPS + e3)), d);

        f32x4 ov;
        if (use_sqrt) {
            ov.x = fast_sqrt(y0) - d_pow;
            ov.y = fast_sqrt(y1) - d_pow;
            ov.z = fast_sqrt(y2) - d_pow;
            ov.w = fast_sqrt(y3) - d_pow;
        } else {
            ov.x = fast_exp2(inv_r * fast_log2(y0)) - d_pow;
            ov.y = fast_exp2(inv_r * fast_log2(y1)) - d_pow;
            ov.z = fast_exp2(inv_r * fast_log2(y2)) - d_pow;
            ov.w = fast_exp2(inv_r * fast_log2(y3)) - d_pow;
        }
        if (valid) __builtin_nontemporal_store(ov, &op[g]);
    }
}

extern "C" void kernel_launch(void* const* d_in, const int* in_sizes, int n_in,
                              void* d_out, int out_size, void* d_ws, size_t ws_size,
                              hipStream_t stream) {
    const float* x     = (const float*)d_in[0];
    const float* alpha = (const float*)d_in[1];
    const float* delta = (const float*)d_in[2];
    const float* root  = (const float*)d_in[3];
    const float* ema_w = (const float*)d_in[4];
    float* out = (float*)d_out;

    const int total_waves = N_ROWS * CHUNKS;                                 // 20480
    const int grid = (total_waves + WAVES_PER_BLOCK - 1) / WAVES_PER_BLOCK;  // 5120
    pcen_kernel<<<grid, 256, 0, stream>>>(x, alpha, delta, root, ema_w, out);
}

// Round 5
// 56.379 us; speedup vs baseline: 7.4262x; 7.4262x over previous
//
#include <hip/hip_runtime.h>
#include <math.h>

#define FLOOR_EPS 1e-6f
#define T_LEN 8000
#define C_CH 40
#define N_ROWS (128 * 40)
#define CHUNKS 4
#define CHUNK_LEN (T_LEN / CHUNKS)   // 2000
#define NTILES 8                     // 8 tiles x 256 elems (last tile 208)
#define LOOKBACK 512                 // q^512 = 0.96^512 ~ 8.6e-10 -> exact to fp32
#define WAVES_PER_BLOCK 4

typedef float f32x4 __attribute__((ext_vector_type(4)));

__device__ __forceinline__ float fast_log2(float v) { return __builtin_amdgcn_logf(v); }
__device__ __forceinline__ float fast_exp2(float v) { return __builtin_amdgcn_exp2f(v); }
__device__ __forceinline__ float fast_sqrt(float v) { return __builtin_amdgcn_sqrtf(v); }

// One wave per (row, chunk); R3's coalesced interleaved layout (lane l owns
// elems l*4..l*4+3 of each 256-elem tile). All 8 tile loads issue upfront;
// the 8 per-tile shuffle-scans run INTERLEAVED (latency-parallel); the only
// serial part is the 8-step carry fmaf chain.
// EMA: s_t = q*s_{t-1} + w*x_t, s_{-1} = x[0].
__global__ __launch_bounds__(256) void pcen_kernel(
    const float* __restrict__ x,
    const float* __restrict__ alpha,
    const float* __restrict__ delta,
    const float* __restrict__ root,
    const float* __restrict__ ema_w,
    float* __restrict__ out)
{
    const int wave  = threadIdx.x >> 6;
    const int lane  = threadIdx.x & 63;
    const int gid   = blockIdx.x * WAVES_PER_BLOCK + wave;
    const int row   = gid >> 2;          // CHUNKS == 4
    const int chunk = gid & 3;
    if (row >= N_ROWS) return;
    const int c = row % C_CH;

    const float w     = fminf(fmaxf(ema_w[c], 0.0f), 1.0f);
    const float q     = 1.0f - w;
    const float a     = fminf(alpha[c], 1.0f);
    const float inv_r = 1.0f / fmaxf(root[c], 1.0f);
    const float d     = delta[c];
    const float d_pow = powf(d, inv_r);
    const bool  use_sqrt = (inv_r == 0.5f);

    // q^(4*2^k), k=0..5 (scan weights), q^256 (tile carry)
    float q4p[6];
    q4p[0] = (q * q) * (q * q);
    #pragma unroll
    for (int k = 1; k < 6; ++k) q4p[k] = q4p[k - 1] * q4p[k - 1];
    const float q256 = q4p[5] * q4p[5];

    // qp = q^(4*lane)
    float qp = 1.0f;
    #pragma unroll
    for (int k = 0; k < 6; ++k)
        if ((lane >> k) & 1) qp *= q4p[k];

    const int base  = row * T_LEN + chunk * CHUNK_LEN;
    const int vbase = base >> 2;

    // ---- all 8 tile loads upfront (coalesced float4) ----
    float4 xv[NTILES];
    #pragma unroll
    for (int t = 0; t < NTILES; ++t) {
        const int  eidx   = t * 256 + lane * 4;
        const bool active = eidx < CHUNK_LEN;
        xv[t] = active ? ((const float4*)x)[vbase + t * 64 + lane]
                       : make_float4(0.f, 0.f, 0.f, 0.f);
    }

    // ---- incoming state for the chunk ----
    float sc;
    if (chunk == 0) {
        sc = __shfl(xv[0].x, 0, 64);     // s_{-1} = x[0]
    } else {
        // ema[base-1] ~= sum_{j<512} w q^j x[base-1-j]  (wave reduction)
        // q^(8*2^k) for the lane scale:
        float q8p[6];
        q8p[0] = q4p[0] * q4p[0];
        #pragma unroll
        for (int k = 1; k < 6; ++k) q8p[k] = q8p[k - 1] * q8p[k - 1];

        const float4* lp = (const float4*)(x + (size_t)row * T_LEN
                                           + chunk * CHUNK_LEN - LOOKBACK + lane * 8);
        float4 a0 = lp[0];
        float4 a1 = lp[1];
        float v = a0.x;
        v = fmaf(v, q, a0.y); v = fmaf(v, q, a0.z); v = fmaf(v, q, a0.w);
        v = fmaf(v, q, a1.x); v = fmaf(v, q, a1.y); v = fmaf(v, q, a1.z); v = fmaf(v, q, a1.w);
        float S = w * v;
        const int m = 63 - lane;         // scale = q^(8*m)
        float scale = 1.0f;
        #pragma unroll
        for (int k = 0; k < 6; ++k)
            if ((m >> k) & 1) scale *= q8p[k];
        S *= scale;
        #pragma unroll
        for (int k = 0; k < 6; ++k)
            S += __shfl_xor(S, 1 << k, 64);
        sc = S;
    }

    // ---- per-tile lane-local folds (independent, ILP) ----
    float B[NTILES];
    #pragma unroll
    for (int t = 0; t < NTILES; ++t) {
        float b = xv[t].x;
        b = fmaf(b, q, xv[t].y);
        b = fmaf(b, q, xv[t].z);
        b = fmaf(b, q, xv[t].w);
        B[t] = w * b;
    }

    // ---- 8 interleaved inclusive wave scans (k outer -> latency overlap) ----
    #pragma unroll
    for (int k = 0; k < 6; ++k) {
        float Bp[NTILES];
        #pragma unroll
        for (int t = 0; t < NTILES; ++t) Bp[t] = __shfl_up(B[t], 1u << k, 64);
        #pragma unroll
        for (int t = 0; t < NTILES; ++t)
            if (lane >= (1 << k)) B[t] = fmaf(q4p[k], Bp[t], B[t]);
    }

    // ---- tile-end totals (independent broadcasts) ----
    float Blast[NTILES];
    #pragma unroll
    for (int t = 0; t < NTILES; ++t) Blast[t] = __shfl(B[t], 63, 64);

    // ---- per-tile outputs; serial part is just sc = fmaf(q256, sc, Blast) ----
    #pragma unroll
    for (int t = 0; t < NTILES; ++t) {
        float Bexcl = __shfl_up(B[t], 1, 64);
        if (lane == 0) Bexcl = 0.0f;

        float s  = fmaf(qp, sc, Bexcl);
        float e0 = fmaf(q, s,  w * xv[t].x);
        float e1 = fmaf(q, e0, w * xv[t].y);
        float e2 = fmaf(q, e1, w * xv[t].z);
        float e3 = fmaf(q, e2, w * xv[t].w);

        float y0 = fmaf(xv[t].x, fast_exp2(-a * fast_log2(FLOOR_EPS + e0)), d);
        float y1 = fmaf(xv[t].y, fast_exp2(-a * fast_log2(FLOOR_EPS + e1)), d);
        float y2 = fmaf(xv[t].z, fast_exp2(-a * fast_log2(FLOOR_EPS + e2)), d);
        float y3 = fmaf(xv[t].w, fast_exp2(-a * fast_log2(FLOOR_EPS + e3)), d);

        f32x4 ov;
        if (use_sqrt) {
            ov.x = fast_sqrt(y0) - d_pow;
            ov.y = fast_sqrt(y1) - d_pow;
            ov.z = fast_sqrt(y2) - d_pow;
            ov.w = fast_sqrt(y3) - d_pow;
        } else {
            ov.x = fast_exp2(inv_r * fast_log2(y0)) - d_pow;
            ov.y = fast_exp2(inv_r * fast_log2(y1)) - d_pow;
            ov.z = fast_exp2(inv_r * fast_log2(y2)) - d_pow;
            ov.w = fast_exp2(inv_r * fast_log2(y3)) - d_pow;
        }

        const int eidx = t * 256 + lane * 4;
        if (eidx < CHUNK_LEN)
            __builtin_nontemporal_store(ov, &((f32x4*)out)[vbase + t * 64 + lane]);

        sc = fmaf(q256, sc, Blast[t]);   // carry to next tile (8 fmaf total)
    }
}

extern "C" void kernel_launch(void* const* d_in, const int* in_sizes, int n_in,
                              void* d_out, int out_size, void* d_ws, size_t ws_size,
                              hipStream_t stream) {
    const float* x     = (const float*)d_in[0];
    const float* alpha = (const float*)d_in[1];
    const float* delta = (const float*)d_in[2];
    const float* root  = (const float*)d_in[3];
    const float* ema_w = (const float*)d_in[4];
    float* out = (float*)d_out;

    const int total_waves = N_ROWS * CHUNKS;                                 // 20480
    const int grid = (total_waves + WAVES_PER_BLOCK - 1) / WAVES_PER_BLOCK;  // 5120
    pcen_kernel<<<grid, 256, 0, stream>>>(x, alpha, delta, root, ema_w, out);
}